// Round 3
// baseline (209.032 us; speedup 1.0000x reference)
//
#include <hip/hip_runtime.h>

// Problem constants (reference: b=16, c=2048, h=56, w=56, K=3, PAD=1)
#define BATCH   16
#define CH      2048
#define HW      3136   // 56*56
#define HW4     784    // HW/4 (3136 % 4 == 0 -> float4 chunks never cross planes)
#define NPLANES (BATCH * CH)

// Batch-group pipelining: 4 batches per group = 103 MB of x, fully
// Infinity-Cache(256MB)-resident between the mean pass and the scale pass.
#define NGROUPS          4
#define BATCH_PER_GROUP  (BATCH / NGROUPS)            // 4
#define PLANES_PER_GROUP (BATCH_PER_GROUP * CH)       // 8192

typedef float v4f __attribute__((ext_vector_type(4)));

// ---------------------------------------------------------------------------
// Kernel 1: per-(b,c) mean over the 56x56 plane, for one batch-group.
// One block per plane; plane data is contiguous (NCHW). float4 loads.
// Normal (caching) loads on purpose: these lines must be L3-resident for the
// scale pass that follows.
// ---------------------------------------------------------------------------
__global__ __launch_bounds__(256) void mean_kernel(const float* __restrict__ x,
                                                   float* __restrict__ y,
                                                   int plane_base) {
    const int plane = plane_base + (int)blockIdx.x;  // b*CH + c
    const v4f* xp = reinterpret_cast<const v4f*>(x) + (size_t)plane * HW4;

    float sum = 0.0f;
    for (int i = threadIdx.x; i < HW4; i += 256) {
        v4f v = xp[i];
        sum += (v.x + v.y) + (v.z + v.w);
    }
    // wave-64 reduce
    #pragma unroll
    for (int o = 32; o > 0; o >>= 1) sum += __shfl_down(sum, o, 64);

    __shared__ float part[4];
    const int lane = threadIdx.x & 63;
    const int wid  = threadIdx.x >> 6;
    if (lane == 0) part[wid] = sum;
    __syncthreads();
    if (threadIdx.x == 0) {
        float s = (part[0] + part[1]) + (part[2] + part[3]);
        y[plane] = s * (1.0f / (float)HW);
    }
}

// ---------------------------------------------------------------------------
// Kernel 2: out = x * gate(plane) for one batch-group. The group's x planes
// were just streamed by mean_kernel, so reads hit L3. Non-temporal stores so
// the 103 MB/group write stream doesn't evict the next group's x.
//
// Gate math (matches jax reference):
//   offsets[k] = sum_j y[c+j-1] * w_offset[k,0,j]   (zero-padded)
//   p = c + (k-1) + offsets[k]; clip [0, C-1]; linear-interp sample of y;
//   gate = sigmoid( sum_k sample_k * w_deform[k] + b_deform )
// ---------------------------------------------------------------------------
__global__ __launch_bounds__(256) void scale_kernel(const float* __restrict__ x,
                                                    const float* __restrict__ y,
                                                    const float* __restrict__ w_offset,
                                                    const float* __restrict__ w_deform,
                                                    const float* __restrict__ b_deform,
                                                    float* __restrict__ out,
                                                    int plane_base) {
    const int plane = plane_base + (int)blockIdx.x;
    __shared__ float sgate;

    if (threadIdx.x == 0) {
        const int b = plane >> 11;          // / CH
        const int c = plane & (CH - 1);     // % CH
        const float* yb = y + b * CH;

        const float ym = (c >= 1)      ? yb[c - 1] : 0.0f;  // zero padding
        const float y0 = yb[c];
        const float yp = (c < CH - 1)  ? yb[c + 1] : 0.0f;

        float acc = 0.0f;
        #pragma unroll
        for (int k = 0; k < 3; ++k) {
            const float off = ym * w_offset[k * 3 + 0]
                            + y0 * w_offset[k * 3 + 1]
                            + yp * w_offset[k * 3 + 2];
            float p = (float)c + (float)(k - 1) + off;
            p = fminf(fmaxf(p, 0.0f), (float)(CH - 1));
            const float p0 = floorf(p);
            const float fr = p - p0;
            const int i0 = (int)p0;
            const int i1 = min(i0 + 1, CH - 1);
            const float s = yb[i0] * (1.0f - fr) + yb[i1] * fr;
            acc += s * w_deform[k];
        }
        const float v = acc + b_deform[0];
        sgate = 1.0f / (1.0f + expf(-v));
    }
    __syncthreads();
    const float g = sgate;

    const v4f* xp = reinterpret_cast<const v4f*>(x)   + (size_t)plane * HW4;
    v4f*       op = reinterpret_cast<v4f*>(out)       + (size_t)plane * HW4;
    for (int i = threadIdx.x; i < HW4; i += 256) {
        v4f v = xp[i];            // L3 hit: this plane was read by mean_kernel
        v *= g;
        __builtin_nontemporal_store(v, &op[i]);  // don't evict x with writes
    }
}

extern "C" void kernel_launch(void* const* d_in, const int* in_sizes, int n_in,
                              void* d_out, int out_size, void* d_ws, size_t ws_size,
                              hipStream_t stream) {
    const float* x        = (const float*)d_in[0];   // (16, 2048, 56, 56)
    const float* w_offset = (const float*)d_in[1];   // (3, 1, 3)
    const float* w_deform = (const float*)d_in[2];   // (3,)
    const float* b_deform = (const float*)d_in[3];   // (1,)
    float* out = (float*)d_out;

    float* y = (float*)d_ws;                          // BATCH*CH floats

    // Per-group: mean pass then scale pass; stream order is the barrier.
    // Group x footprint (103 MB) stays L3-resident between the two passes.
    for (int g = 0; g < NGROUPS; ++g) {
        const int plane_base = g * PLANES_PER_GROUP;
        mean_kernel<<<PLANES_PER_GROUP, 256, 0, stream>>>(x, y, plane_base);
        scale_kernel<<<PLANES_PER_GROUP, 256, 0, stream>>>(x, y, w_offset, w_deform,
                                                           b_deform, out, plane_base);
    }
}

// Round 4
// 193.851 us; speedup vs baseline: 1.0783x; 1.0783x over previous
//
#include <hip/hip_runtime.h>

// Problem constants (reference: b=16, c=2048, h=56, w=56, K=3, PAD=1)
#define BATCH   16
#define CH      2048
#define HW      3136   // 56*56
#define HW4     784    // HW/4 (3136 % 4 == 0 -> float4 chunks never cross planes)
#define NPLANES (BATCH * CH)

typedef float v4f __attribute__((ext_vector_type(4)));

// ---------------------------------------------------------------------------
// Kernel 1: per-(b,c) mean over the 56x56 plane.
// One block per plane; plane data is contiguous (NCHW). float4 loads.
// ---------------------------------------------------------------------------
__global__ __launch_bounds__(256) void mean_kernel(const float* __restrict__ x,
                                                   float* __restrict__ y) {
    const int plane = blockIdx.x;  // b*CH + c
    const v4f* xp = reinterpret_cast<const v4f*>(x) + (size_t)plane * HW4;

    float sum = 0.0f;
    for (int i = threadIdx.x; i < HW4; i += 256) {
        v4f v = xp[i];
        sum += (v.x + v.y) + (v.z + v.w);
    }
    // wave-64 reduce
    #pragma unroll
    for (int o = 32; o > 0; o >>= 1) sum += __shfl_down(sum, o, 64);

    __shared__ float part[4];
    const int lane = threadIdx.x & 63;
    const int wid  = threadIdx.x >> 6;
    if (lane == 0) part[wid] = sum;
    __syncthreads();
    if (threadIdx.x == 0) {
        float s = (part[0] + part[1]) + (part[2] + part[3]);
        y[plane] = s * (1.0f / (float)HW);
    }
}

// ---------------------------------------------------------------------------
// Kernel 2: out = x * gate(plane). Gate computed per-block by thread 0 from
// the y row (y is 128 KB, L2-resident). Plane order reversed vs the mean
// kernel; non-temporal stores keep the write stream from evicting x.
//
// Gate math (matches jax reference):
//   offsets[k] = sum_j y[c+j-1] * w_offset[k,0,j]   (zero-padded)
//   p = c + (k-1) + offsets[k]; clip [0, C-1]; linear-interp sample of y;
//   gate = sigmoid( sum_k sample_k * w_deform[k] + b_deform )
// ---------------------------------------------------------------------------
__global__ __launch_bounds__(256) void scale_kernel(const float* __restrict__ x,
                                                    const float* __restrict__ y,
                                                    const float* __restrict__ w_offset,
                                                    const float* __restrict__ w_deform,
                                                    const float* __restrict__ b_deform,
                                                    float* __restrict__ out) {
    const int plane = (NPLANES - 1) - (int)blockIdx.x;  // reverse order
    __shared__ float sgate;

    if (threadIdx.x == 0) {
        const int b = plane >> 11;          // / CH
        const int c = plane & (CH - 1);     // % CH
        const float* yb = y + b * CH;

        const float ym = (c >= 1)      ? yb[c - 1] : 0.0f;  // zero padding
        const float y0 = yb[c];
        const float yp = (c < CH - 1)  ? yb[c + 1] : 0.0f;

        float acc = 0.0f;
        #pragma unroll
        for (int k = 0; k < 3; ++k) {
            const float off = ym * w_offset[k * 3 + 0]
                            + y0 * w_offset[k * 3 + 1]
                            + yp * w_offset[k * 3 + 2];
            float p = (float)c + (float)(k - 1) + off;
            p = fminf(fmaxf(p, 0.0f), (float)(CH - 1));
            const float p0 = floorf(p);
            const float fr = p - p0;
            const int i0 = (int)p0;
            const int i1 = min(i0 + 1, CH - 1);
            const float s = yb[i0] * (1.0f - fr) + yb[i1] * fr;
            acc += s * w_deform[k];
        }
        const float v = acc + b_deform[0];
        sgate = 1.0f / (1.0f + expf(-v));
    }
    __syncthreads();
    const float g = sgate;

    const v4f* xp = reinterpret_cast<const v4f*>(x)   + (size_t)plane * HW4;
    v4f*       op = reinterpret_cast<v4f*>(out)       + (size_t)plane * HW4;
    for (int i = threadIdx.x; i < HW4; i += 256) {
        v4f v = xp[i];
        v *= g;
        __builtin_nontemporal_store(v, &op[i]);
    }
}

extern "C" void kernel_launch(void* const* d_in, const int* in_sizes, int n_in,
                              void* d_out, int out_size, void* d_ws, size_t ws_size,
                              hipStream_t stream) {
    const float* x        = (const float*)d_in[0];   // (16, 2048, 56, 56)
    const float* w_offset = (const float*)d_in[1];   // (3, 1, 3)
    const float* w_deform = (const float*)d_in[2];   // (3,)
    const float* b_deform = (const float*)d_in[3];   // (1,)
    float* out = (float*)d_out;

    float* y = (float*)d_ws;                          // BATCH*CH floats

    mean_kernel<<<NPLANES, 256, 0, stream>>>(x, y);
    scale_kernel<<<NPLANES, 256, 0, stream>>>(x, y, w_offset, w_deform, b_deform, out);
}